// Round 10
// baseline (412.684 us; speedup 1.0000x reference)
//
#include <hip/hip_runtime.h>
#include <hip/hip_bf16.h>
#include <math.h>

#define B_      4
#define LQ_     512
#define LKV_    4096
#define IN_DIM_ 1024
#define NH_     16
#define DH_     64
#define INNER_  1024

typedef _Float16 f16x8 __attribute__((ext_vector_type(8)));
typedef _Float16 f16x4 __attribute__((ext_vector_type(4)));
typedef float    f32x4 __attribute__((ext_vector_type(4)));

// async global->LDS, 16B per lane; LDS dest = wave-uniform base + lane*16
#define GLDS(gp, lp) __builtin_amdgcn_global_load_lds( \
    (const __attribute__((address_space(1))) void*)(gp), \
    (__attribute__((address_space(3))) void*)(lp), 16, 0, 0)

// ---------------------------------------------------------------------------
// Per-batch mask scan (coalesced int4 + shfl scan): pidx = excl prefix, cnt.
// Also zeroes the 512 attn finalize tickets (d_ws is re-poisoned each launch).
// ---------------------------------------------------------------------------
__global__ __launch_bounds__(256) void scan_mask(const int* __restrict__ mask,
                                                 int* __restrict__ pidx,
                                                 int* __restrict__ cnt,
                                                 int* __restrict__ tick) {
  __shared__ int wsum_s[4];
  int b = blockIdx.x, tid = threadIdx.x;
  if (tid < 128) tick[b * 128 + tid] = 0;
  const int* mb = mask + b * LKV_;
  int base = tid * 16;
  int vals[16];
#pragma unroll
  for (int i = 0; i < 4; ++i) {
    int4 v = *(const int4*)(mb + base + i * 4);
    vals[i * 4 + 0] = v.x; vals[i * 4 + 1] = v.y;
    vals[i * 4 + 2] = v.z; vals[i * 4 + 3] = v.w;
  }
  int s = 0;
#pragma unroll
  for (int j = 0; j < 16; ++j) s += (vals[j] == 0);
  int lane = tid & 63, wave = tid >> 6;
  int inc = s;
#pragma unroll
  for (int d = 1; d < 64; d <<= 1) {
    int v = __shfl_up(inc, d);
    if (lane >= d) inc += v;
  }
  if (lane == 63) wsum_s[wave] = inc;
  __syncthreads();
  int woff = 0;
#pragma unroll
  for (int w = 0; w < 4; ++w)
    if (w < wave) woff += wsum_s[w];
  if (tid == 255) cnt[b] = woff + inc;
  int run = woff + inc - s;
#pragma unroll
  for (int i = 0; i < 4; ++i) {
    int4 o;
    int* op = &o.x;
#pragma unroll
    for (int j = 0; j < 4; ++j) { op[j] = run; run += (vals[i * 4 + j] == 0); }
    *(int4*)(pidx + b * LKV_ + base + i * 4) = o;
  }
}

// ---------------------------------------------------------------------------
// Fused prep: [0,16384) compact kv | [16384,18432) q cast |
// [18432,19456) Wq^T | [19456,21504) Wkv^T | [21504,22528) Wo^T.
// ---------------------------------------------------------------------------
__device__ __forceinline__ void transpose_tile(const float* __restrict__ in,
                                               _Float16* __restrict__ out,
                                               int K, int N, int xb, int yb,
                                               float (*t)[33]) {
  int bn = xb * 32, bk = yb * 32;
  int tx = threadIdx.x & 31, ty = threadIdx.x >> 5;
#pragma unroll
  for (int i = 0; i < 4; ++i) {
    int r = ty + i * 8;
    t[r][tx] = in[(size_t)(bk + r) * N + bn + tx];
  }
  __syncthreads();
#pragma unroll
  for (int i = 0; i < 4; ++i) {
    int r = ty + i * 8;
    out[(size_t)(bn + r) * K + bk + tx] = (_Float16)t[tx][r];
  }
}

__global__ __launch_bounds__(256) void prep_compact(
    const float* __restrict__ kv, const float* __restrict__ q,
    const float* __restrict__ Wq, const float* __restrict__ Wkv,
    const float* __restrict__ Wo, const int* __restrict__ mask,
    const int* __restrict__ pidx,
    _Float16* __restrict__ kv16, _Float16* __restrict__ q16,
    _Float16* __restrict__ Wqt, _Float16* __restrict__ Wkvt,
    _Float16* __restrict__ Wot) {
  __shared__ float t[32][33];
  const int id = blockIdx.x, tid = threadIdx.x;
  if (id < 16384) {  // compact + cast kv row
    if (mask[id] != 0) return;
    int b = id >> 12;
    int dst = b * LKV_ + pidx[id];
    float4 v = ((const float4*)(kv + (size_t)id * IN_DIM_))[tid];
    f16x4 h = {(_Float16)v.x, (_Float16)v.y, (_Float16)v.z, (_Float16)v.w};
    ((f16x4*)(kv16 + (size_t)dst * IN_DIM_))[tid] = h;
  } else if (id < 18432) {  // q cast
    int i = (id - 16384) * 256 + tid;
    float4 v = ((const float4*)q)[i];
    f16x4 h = {(_Float16)v.x, (_Float16)v.y, (_Float16)v.z, (_Float16)v.w};
    ((f16x4*)q16)[i] = h;
  } else if (id < 19456) {
    int l = id - 18432;
    transpose_tile(Wq, Wqt, 1024, 1024, l & 31, l >> 5, t);
  } else if (id < 21504) {
    int l = id - 19456;
    transpose_tile(Wkv, Wkvt, 1024, 2048, l & 63, l >> 6, t);
  } else {
    int l = id - 21504;
    transpose_tile(Wo, Wot, 1024, 1024, l & 31, l >> 5, t);
  }
}

// ---------------------------------------------------------------------------
// Fused projection GEMM (fp16 MFMA, 128x128 tile, BK=128 -> 8 K-steps,
// 64 MFMA per wave per barrier-pair).
// blocks [0,2048): kvp -> split Kp / transposed Vt, early exit past cnt[b].
// blocks [2048,2176): qp16 = q16 @ Wqt^T.
// ---------------------------------------------------------------------------
__global__ __launch_bounds__(256, 2) void proj_f16(
    const _Float16* __restrict__ kv16, const _Float16* __restrict__ Wkvt,
    const _Float16* __restrict__ q16, const _Float16* __restrict__ Wqt,
    _Float16* __restrict__ qp16, _Float16* __restrict__ Kp,
    _Float16* __restrict__ Vt, const int* __restrict__ Cnt) {
  const int id = blockIdx.x;
  const bool is_kv = (id < 2048);
  int brow, bcol;
  const _Float16 *Ab, *Bb;
  if (is_kv) {
    bcol = (id & 15) * 128;
    brow = (id >> 4) * 128;
    if ((brow & 4095) >= Cnt[brow >> 12]) return;
    Ab = kv16 + (size_t)brow * 1024;
    Bb = Wkvt + (size_t)bcol * 1024;
  } else {
    int l = id - 2048;
    bcol = (l & 7) * 128;
    brow = (l >> 3) * 128;
    Ab = q16 + (size_t)brow * 1024;
    Bb = Wqt + (size_t)bcol * 1024;
  }
  __shared__ _Float16 As[128 * 128];
  __shared__ _Float16 Bs[128 * 128];
  const int tid = threadIdx.x;
  const int wave = tid >> 6, lane = tid & 63;
  const int quad = lane >> 4, l16 = lane & 15;
  const int wm = (wave & 1) * 64, wn = (wave >> 1) * 64;
  const int r4 = lane >> 4, ch = lane & 15;  // stage: 4 rows x 16 chunks

  f32x4 acc[4][4];
#pragma unroll
  for (int i = 0; i < 4; ++i)
#pragma unroll
    for (int j = 0; j < 4; ++j) acc[i][j] = (f32x4){0.f, 0.f, 0.f, 0.f};

  for (int k0 = 0; k0 < 1024; k0 += 128) {
    __syncthreads();
#pragma unroll
    for (int i = 0; i < 8; ++i) {
      int rbase = wave * 32 + i * 4;
      int row = rbase + r4;
      int g = ch ^ (row & 15);
      GLDS(Ab + (size_t)row * 1024 + k0 + g * 8, &As[rbase * 128]);
      GLDS(Bb + (size_t)row * 1024 + k0 + g * 8, &Bs[rbase * 128]);
    }
    __syncthreads();
#pragma unroll
    for (int ks = 0; ks < 4; ++ks) {
      f16x8 af[4], bf[4];
      int c = ks * 4 + quad;
#pragma unroll
      for (int mt = 0; mt < 4; ++mt) {
        int r = wm + mt * 16 + l16;
        af[mt] = *(const f16x8*)&As[r * 128 + ((c ^ (r & 15)) * 8)];
        int rb = wn + mt * 16 + l16;
        bf[mt] = *(const f16x8*)&Bs[rb * 128 + ((c ^ (rb & 15)) * 8)];
      }
#pragma unroll
      for (int mt = 0; mt < 4; ++mt)
#pragma unroll
        for (int nt = 0; nt < 4; ++nt)
          acc[mt][nt] = __builtin_amdgcn_mfma_f32_16x16x32_f16(af[mt], bf[nt], acc[mt][nt], 0, 0, 0);
    }
  }

#pragma unroll
  for (int mt = 0; mt < 4; ++mt) {
    int row0 = brow + wm + mt * 16 + quad * 4;
#pragma unroll
    for (int nt = 0; nt < 4; ++nt) {
      int col = bcol + wn + nt * 16 + l16;
      f32x4 v = acc[mt][nt];
      if (is_kv) {
        int h = col >> 7, w64 = col & 63;
        if ((col & 127) < 64) {  // K half
#pragma unroll
          for (int r = 0; r < 4; ++r)
            Kp[(size_t)(row0 + r) * INNER_ + h * 64 + w64] = (_Float16)v[r];
        } else {  // V half, transposed store: regs = 4 consecutive keys
          int b = row0 >> 12, key = row0 & 4095;
          f16x4 pk = {(_Float16)v[0], (_Float16)v[1], (_Float16)v[2], (_Float16)v[3]};
          *(f16x4*)&Vt[((size_t)((b * NH_ + h) * DH_) + w64) * LKV_ + key] = pk;
        }
      } else {
#pragma unroll
        for (int r = 0; r < 4; ++r)
          qp16[(size_t)(row0 + r) * 1024 + col] = (_Float16)v[r];
      }
    }
  }
}

// ---------------------------------------------------------------------------
// Flash attention, key-split x2, FUSED finalize. Grid 1024: bh=id&63
// (XCD-sticky), qt=(id>>6)&7, half=id>>9. Fixed-shift softmax p=exp(s-8).
// Each block writes its fp32 partial, then the LAST arriver of each
// (qt,bh) pair (device-scope ticket) combines partner partial (own half
// still in registers), normalizes, writes ctx16. Removes the attn_fin
// launch + 20 MB HBM round-trip; arithmetic bitwise-identical.
// ---------------------------------------------------------------------------
__global__ __launch_bounds__(256, 2) void attn_f16(
    const _Float16* __restrict__ qp, const _Float16* __restrict__ Kp,
    const _Float16* __restrict__ Vt, const int* __restrict__ cnt,
    float* __restrict__ opart, float* __restrict__ lpart,
    _Float16* __restrict__ ctx, int* __restrict__ tick) {
  const int idx = blockIdx.x;
  const int bh = idx & 63, qt = (idx >> 6) & 7, half = idx >> 9;
  const int b = bh >> 4, h = bh & 15;
  __shared__ _Float16 Ks[128 * 64];    // [key][dim], 8-chunk XOR swizzle
  __shared__ _Float16 Vts[64 * 128];   // [dim][key], 16-chunk XOR swizzle
  __shared__ _Float16 Pl[64][136];     // [query][key], +8 pad
  __shared__ int flag_s;

  const int tid = threadIdx.x;
  const int wave = tid >> 6, lane = tid & 63;
  const int quad = lane >> 4, l16 = lane & 15;
  const int ro8 = lane >> 3, gch8 = (lane & 7) ^ (ro8 & 7);
  const int ro16 = lane >> 4, ch16 = lane & 15;

  const int qrow = b * LQ_ + qt * 64 + wave * 16 + l16;
  const _Float16* qpr = qp + (size_t)qrow * INNER_ + h * DH_;
  f16x8 qf[2];
  qf[0] = *(const f16x8*)(qpr + quad * 8);
  qf[1] = *(const f16x8*)(qpr + 32 + quad * 8);

  const int c_act = cnt[b];
  const int tiles = (c_act + 127) >> 7;
  const int htiles = (tiles + 1) >> 1;
  const int t0 = half * htiles;
  const int t1 = (half == 0) ? htiles : tiles;

  float l_run = 0.f;
  f32x4 oacc[4];
#pragma unroll
  for (int i = 0; i < 4; ++i) oacc[i] = (f32x4){0.f, 0.f, 0.f, 0.f};

  const _Float16* kb = Kp + (size_t)(b * LKV_) * INNER_ + h * DH_;
  const _Float16* vb = Vt + (size_t)((b * NH_ + h) * DH_) * LKV_;

  for (int t = t0; t < t1; ++t) {
    __syncthreads();  // prev-iter LDS reads done
#pragma unroll
    for (int i = 0; i < 4; ++i) {
      int rbase = wave * 32 + i * 8;
      GLDS(kb + (size_t)(t * 128 + rbase + ro8) * INNER_ + gch8 * 8, &Ks[rbase * 64]);
    }
#pragma unroll
    for (int i = 0; i < 4; ++i) {
      int rbase = wave * 16 + i * 4;
      int row = rbase + ro16;
      int gch = ch16 ^ (row & 15);
      GLDS(vb + (size_t)row * LKV_ + t * 128 + gch * 8, &Vts[rbase * 128]);
    }
    __syncthreads();  // staged data visible

    // S^T = K . Q^T
    f32x4 sacc[8];
#pragma unroll
    for (int i = 0; i < 8; ++i) sacc[i] = (f32x4){0.f, 0.f, 0.f, 0.f};
#pragma unroll
    for (int ks = 0; ks < 2; ++ks) {
      int c = ks * 4 + quad;
#pragma unroll
      for (int mt = 0; mt < 8; ++mt) {
        int krow = mt * 16 + l16;
        f16x8 af = *(const f16x8*)&Ks[krow * 64 + ((c ^ (krow & 7)) * 8)];
        sacc[mt] = __builtin_amdgcn_mfma_f32_16x16x32_f16(af, qf[ks], sacc[mt], 0, 0, 0);
      }
    }
    // scale + tail mask + exp(s-8) + P pack
    const int lim = c_act - t * 128;
    float psloc = 0.f;
#pragma unroll
    for (int mt = 0; mt < 8; ++mt) {
      f16x4 pk;
#pragma unroll
      for (int r = 0; r < 4; ++r) {
        int key = mt * 16 + quad * 4 + r;
        float s = sacc[mt][r] * 0.125f;
        if (key >= lim) s = -1e30f;
        float p = __expf(s - 8.0f);
        psloc += p;
        pk[r] = (_Float16)p;
      }
      *(f16x4*)&Pl[wave * 16 + l16][mt * 16 + quad * 4] = pk;
    }
    psloc += __shfl_xor(psloc, 16);
    psloc += __shfl_xor(psloc, 32);
    l_run += psloc;
    // O^T += V^T . P^T (within-wave Pl dep: lgkmcnt-ordered, no barrier)
#pragma unroll
    for (int ks = 0; ks < 4; ++ks) {
      int c = ks * 4 + quad;
      f16x8 bf = *(const f16x8*)&Pl[wave * 16 + l16][ks * 32 + quad * 8];
#pragma unroll
      for (int mt = 0; mt < 4; ++mt) {
        int drow = mt * 16 + l16;
        f16x8 af = *(const f16x8*)&Vts[drow * 128 + ((c ^ (drow & 15)) * 8)];
        oacc[mt] = __builtin_amdgcn_mfma_f32_16x16x32_f16(af, bf, oacc[mt], 0, 0, 0);
      }
    }
  }

  // write fp32 partials (no normalization)
  float* ob = opart + ((size_t)(half * 2048 + qrow)) * INNER_ + h * DH_;
#pragma unroll
  for (int mt = 0; mt < 4; ++mt)
    *(f32x4*)(ob + mt * 16 + quad * 4) = oacc[mt];
  if (quad == 0) lpart[(size_t)(half * 2048 + qrow) * NH_ + h] = l_run;

  // last-arriver finalize: release own stores, ticket, acquire partner's
  __threadfence();          // device-scope release of this thread's stores
  __syncthreads();          // all threads' fences precede the ticket
  if (tid == 0) flag_s = atomicAdd(&tick[(qt << 6) | bh], 1);
  __syncthreads();
  if (flag_s == 1) {
    __threadfence();        // acquire: order/invalidate before partner reads
    const int phalf = 1 - half;
    const float* po = opart + ((size_t)(phalf * 2048 + qrow)) * INNER_ + h * DH_;
    float pl = lpart[(size_t)(phalf * 2048 + qrow) * NH_ + h];
    float lt = l_run + pl;
    float inv = (lt > 0.f) ? 1.f / lt : 0.f;
    _Float16* cb = ctx + (size_t)qrow * INNER_ + h * DH_;
#pragma unroll
    for (int mt = 0; mt < 4; ++mt) {
      f32x4 pv = *(const f32x4*)(po + mt * 16 + quad * 4);
      f16x4 ov;
#pragma unroll
      for (int r = 0; r < 4; ++r) ov[r] = (_Float16)((oacc[mt][r] + pv[r]) * inv);
      *(f16x4*)(cb + mt * 16 + quad * 4) = ov;
    }
  }
}

// ---------------------------------------------------------------------------
// Output GEMM: out[2048][1024] f32 = ctx16 @ Wot^T. 64x128 tiles -> 256
// blocks (one per CU), BK=128 -> 8 K-steps.
// ---------------------------------------------------------------------------
__global__ __launch_bounds__(256, 2) void gemm_out(
    const _Float16* __restrict__ A, const _Float16* __restrict__ Bt,
    float* __restrict__ C) {
  const int brow = blockIdx.y * 64, bcol = blockIdx.x * 128;
  __shared__ _Float16 As[64 * 128];
  __shared__ _Float16 Bs[128 * 128];
  const int tid = threadIdx.x;
  const int wave = tid >> 6, lane = tid & 63;
  const int quad = lane >> 4, l16 = lane & 15;
  const int wm = (wave & 1) * 32, wn = (wave >> 1) * 64;
  const int r4 = lane >> 4, ch = lane & 15;

  f32x4 acc[2][4];
#pragma unroll
  for (int i = 0; i < 2; ++i)
#pragma unroll
    for (int j = 0; j < 4; ++j) acc[i][j] = (f32x4){0.f, 0.f, 0.f, 0.f};

  const _Float16* Ab = A + (size_t)brow * 1024;
  const _Float16* Bb = Bt + (size_t)bcol * 1024;

  for (int k0 = 0; k0 < 1024; k0 += 128) {
    __syncthreads();
#pragma unroll
    for (int i = 0; i < 4; ++i) {
      int rbase = wave * 16 + i * 4;
      int row = rbase + r4;
      int g = ch ^ (row & 15);
      GLDS(Ab + (size_t)row * 1024 + k0 + g * 8, &As[rbase * 128]);
    }
#pragma unroll
    for (int i = 0; i < 8; ++i) {
      int rbase = wave * 32 + i * 4;
      int row = rbase + r4;
      int g = ch ^ (row & 15);
      GLDS(Bb + (size_t)row * 1024 + k0 + g * 8, &Bs[rbase * 128]);
    }
    __syncthreads();
#pragma unroll
    for (int ks = 0; ks < 4; ++ks) {
      f16x8 af[2], bf[4];
      int c = ks * 4 + quad;
#pragma unroll
      for (int mt = 0; mt < 2; ++mt) {
        int r = wm + mt * 16 + l16;
        af[mt] = *(const f16x8*)&As[r * 128 + ((c ^ (r & 15)) * 8)];
      }
#pragma unroll
      for (int nt = 0; nt < 4; ++nt) {
        int rb = wn + nt * 16 + l16;
        bf[nt] = *(const f16x8*)&Bs[rb * 128 + ((c ^ (rb & 15)) * 8)];
      }
#pragma unroll
      for (int mt = 0; mt < 2; ++mt)
#pragma unroll
        for (int nt = 0; nt < 4; ++nt)
          acc[mt][nt] = __builtin_amdgcn_mfma_f32_16x16x32_f16(af[mt], bf[nt], acc[mt][nt], 0, 0, 0);
    }
  }

#pragma unroll
  for (int mt = 0; mt < 2; ++mt) {
    int row0 = brow + wm + mt * 16 + quad * 4;
#pragma unroll
    for (int nt = 0; nt < 4; ++nt) {
      int col = bcol + wn + nt * 16 + l16;
      f32x4 v = acc[mt][nt];
#pragma unroll
      for (int r = 0; r < 4; ++r) C[(size_t)(row0 + r) * 1024 + col] = v[r];
    }
  }
}

// ---------------------------------------------------------------------------
extern "C" void kernel_launch(void* const* d_in, const int* in_sizes, int n_in,
                              void* d_out, int out_size, void* d_ws, size_t ws_size,
                              hipStream_t stream) {
  const float* q   = (const float*)d_in[0];
  const float* kv  = (const float*)d_in[1];
  const int* mask  = (const int*)d_in[2];
  const float* Wq  = (const float*)d_in[3];
  const float* Wkv = (const float*)d_in[4];
  const float* Wo  = (const float*)d_in[5];
  float* out = (float*)d_out;

  _Float16* p = (_Float16*)d_ws;
  _Float16* q16   = p; p += (size_t)2048 * 1024;
  _Float16* kv16  = p; p += (size_t)16384 * 1024;  // compacted per-batch
  _Float16* Wqt   = p; p += (size_t)1024 * 1024;
  _Float16* Wkvt  = p; p += (size_t)2048 * 1024;
  _Float16* Wot   = p; p += (size_t)1024 * 1024;
  _Float16* qp16  = p; p += (size_t)2048 * 1024;
  _Float16* Kp    = p; p += (size_t)16384 * 1024;
  _Float16* Vt    = p; p += (size_t)16384 * 1024;
  _Float16* ctx16 = p; p += (size_t)2048 * 1024;
  float* opart = (float*)p; p += (size_t)2 * 4096 * 1024;   // 2x2048x1024 f32
  float* lpart = (float*)p; p += (size_t)2 * 2048 * NH_ * 2; // 2x2048x16 f32
  int* pidx = (int*)p;
  int* cnt  = pidx + 16384;
  int* tick = cnt + 4;               // 512 tickets, zeroed by scan_mask

  scan_mask<<<4, 256, 0, stream>>>(mask, pidx, cnt, tick);
  prep_compact<<<22528, 256, 0, stream>>>(kv, q, Wq, Wkv, Wo, mask, pidx,
                                          kv16, q16, Wqt, Wkvt, Wot);
  proj_f16<<<2176, 256, 0, stream>>>(kv16, Wkvt, q16, Wqt, qp16, Kp, Vt, cnt);
  attn_f16<<<1024, 256, 0, stream>>>(qp16, Kp, Vt, cnt, opart, lpart, ctx16, tick);
  gemm_out<<<dim3(8, 32), 256, 0, stream>>>(ctx16, Wot, out);
}

// Round 11
// 232.172 us; speedup vs baseline: 1.7775x; 1.7775x over previous
//
#include <hip/hip_runtime.h>
#include <hip/hip_bf16.h>
#include <math.h>

#define B_      4
#define LQ_     512
#define LKV_    4096
#define IN_DIM_ 1024
#define NH_     16
#define DH_     64
#define INNER_  1024

typedef _Float16 f16x8 __attribute__((ext_vector_type(8)));
typedef _Float16 f16x4 __attribute__((ext_vector_type(4)));
typedef float    f32x4 __attribute__((ext_vector_type(4)));

// async global->LDS, 16B per lane; LDS dest = wave-uniform base + lane*16
#define GLDS(gp, lp) __builtin_amdgcn_global_load_lds( \
    (const __attribute__((address_space(1))) void*)(gp), \
    (__attribute__((address_space(3))) void*)(lp), 16, 0, 0)

// ---------------------------------------------------------------------------
// Per-batch mask scan (coalesced int4 + shfl scan): pidx = excl prefix, cnt.
// ---------------------------------------------------------------------------
__global__ __launch_bounds__(256) void scan_mask(const int* __restrict__ mask,
                                                 int* __restrict__ pidx,
                                                 int* __restrict__ cnt) {
  __shared__ int wsum_s[4];
  int b = blockIdx.x, tid = threadIdx.x;
  const int* mb = mask + b * LKV_;
  int base = tid * 16;
  int vals[16];
#pragma unroll
  for (int i = 0; i < 4; ++i) {
    int4 v = *(const int4*)(mb + base + i * 4);
    vals[i * 4 + 0] = v.x; vals[i * 4 + 1] = v.y;
    vals[i * 4 + 2] = v.z; vals[i * 4 + 3] = v.w;
  }
  int s = 0;
#pragma unroll
  for (int j = 0; j < 16; ++j) s += (vals[j] == 0);
  int lane = tid & 63, wave = tid >> 6;
  int inc = s;
#pragma unroll
  for (int d = 1; d < 64; d <<= 1) {
    int v = __shfl_up(inc, d);
    if (lane >= d) inc += v;
  }
  if (lane == 63) wsum_s[wave] = inc;
  __syncthreads();
  int woff = 0;
#pragma unroll
  for (int w = 0; w < 4; ++w)
    if (w < wave) woff += wsum_s[w];
  if (tid == 255) cnt[b] = woff + inc;
  int run = woff + inc - s;
#pragma unroll
  for (int i = 0; i < 4; ++i) {
    int4 o;
    int* op = &o.x;
#pragma unroll
    for (int j = 0; j < 4; ++j) { op[j] = run; run += (vals[i * 4 + j] == 0); }
    *(int4*)(pidx + b * LKV_ + base + i * 4) = o;
  }
}

// ---------------------------------------------------------------------------
// Fused prep: [0,16384) compact kv | [16384,18432) q cast |
// [18432,19456) Wq^T | [19456,21504) Wkv^T | [21504,22528) Wo^T.
// ---------------------------------------------------------------------------
__device__ __forceinline__ void transpose_tile(const float* __restrict__ in,
                                               _Float16* __restrict__ out,
                                               int K, int N, int xb, int yb,
                                               float (*t)[33]) {
  int bn = xb * 32, bk = yb * 32;
  int tx = threadIdx.x & 31, ty = threadIdx.x >> 5;
#pragma unroll
  for (int i = 0; i < 4; ++i) {
    int r = ty + i * 8;
    t[r][tx] = in[(size_t)(bk + r) * N + bn + tx];
  }
  __syncthreads();
#pragma unroll
  for (int i = 0; i < 4; ++i) {
    int r = ty + i * 8;
    out[(size_t)(bn + r) * K + bk + tx] = (_Float16)t[tx][r];
  }
}

__global__ __launch_bounds__(256) void prep_compact(
    const float* __restrict__ kv, const float* __restrict__ q,
    const float* __restrict__ Wq, const float* __restrict__ Wkv,
    const float* __restrict__ Wo, const int* __restrict__ mask,
    const int* __restrict__ pidx,
    _Float16* __restrict__ kv16, _Float16* __restrict__ q16,
    _Float16* __restrict__ Wqt, _Float16* __restrict__ Wkvt,
    _Float16* __restrict__ Wot) {
  __shared__ float t[32][33];
  const int id = blockIdx.x, tid = threadIdx.x;
  if (id < 16384) {  // compact + cast kv row
    if (mask[id] != 0) return;
    int b = id >> 12;
    int dst = b * LKV_ + pidx[id];
    float4 v = ((const float4*)(kv + (size_t)id * IN_DIM_))[tid];
    f16x4 h = {(_Float16)v.x, (_Float16)v.y, (_Float16)v.z, (_Float16)v.w};
    ((f16x4*)(kv16 + (size_t)dst * IN_DIM_))[tid] = h;
  } else if (id < 18432) {  // q cast
    int i = (id - 16384) * 256 + tid;
    float4 v = ((const float4*)q)[i];
    f16x4 h = {(_Float16)v.x, (_Float16)v.y, (_Float16)v.z, (_Float16)v.w};
    ((f16x4*)q16)[i] = h;
  } else if (id < 19456) {
    int l = id - 18432;
    transpose_tile(Wq, Wqt, 1024, 1024, l & 31, l >> 5, t);
  } else if (id < 21504) {
    int l = id - 19456;
    transpose_tile(Wkv, Wkvt, 1024, 2048, l & 63, l >> 6, t);
  } else {
    int l = id - 21504;
    transpose_tile(Wo, Wot, 1024, 1024, l & 31, l >> 5, t);
  }
}

// ---------------------------------------------------------------------------
// Fused projection GEMM (fp16 MFMA, 128x128 tile, BK=128 -> 8 K-steps,
// 64 MFMA per wave per barrier-pair).
// blocks [0,2048): kvp -> split Kp / transposed Vt, early exit past cnt[b].
// blocks [2048,2176): qp16 = q16 @ Wqt^T.
// ---------------------------------------------------------------------------
__global__ __launch_bounds__(256, 2) void proj_f16(
    const _Float16* __restrict__ kv16, const _Float16* __restrict__ Wkvt,
    const _Float16* __restrict__ q16, const _Float16* __restrict__ Wqt,
    _Float16* __restrict__ qp16, _Float16* __restrict__ Kp,
    _Float16* __restrict__ Vt, const int* __restrict__ Cnt) {
  const int id = blockIdx.x;
  const bool is_kv = (id < 2048);
  int brow, bcol;
  const _Float16 *Ab, *Bb;
  if (is_kv) {
    bcol = (id & 15) * 128;
    brow = (id >> 4) * 128;
    if ((brow & 4095) >= Cnt[brow >> 12]) return;
    Ab = kv16 + (size_t)brow * 1024;
    Bb = Wkvt + (size_t)bcol * 1024;
  } else {
    int l = id - 2048;
    bcol = (l & 7) * 128;
    brow = (l >> 3) * 128;
    Ab = q16 + (size_t)brow * 1024;
    Bb = Wqt + (size_t)bcol * 1024;
  }
  __shared__ _Float16 As[128 * 128];
  __shared__ _Float16 Bs[128 * 128];
  const int tid = threadIdx.x;
  const int wave = tid >> 6, lane = tid & 63;
  const int quad = lane >> 4, l16 = lane & 15;
  const int wm = (wave & 1) * 64, wn = (wave >> 1) * 64;
  const int r4 = lane >> 4, ch = lane & 15;  // stage: 4 rows x 16 chunks

  f32x4 acc[4][4];
#pragma unroll
  for (int i = 0; i < 4; ++i)
#pragma unroll
    for (int j = 0; j < 4; ++j) acc[i][j] = (f32x4){0.f, 0.f, 0.f, 0.f};

  for (int k0 = 0; k0 < 1024; k0 += 128) {
    __syncthreads();
#pragma unroll
    for (int i = 0; i < 8; ++i) {
      int rbase = wave * 32 + i * 4;
      int row = rbase + r4;
      int g = ch ^ (row & 15);
      GLDS(Ab + (size_t)row * 1024 + k0 + g * 8, &As[rbase * 128]);
      GLDS(Bb + (size_t)row * 1024 + k0 + g * 8, &Bs[rbase * 128]);
    }
    __syncthreads();
#pragma unroll
    for (int ks = 0; ks < 4; ++ks) {
      f16x8 af[4], bf[4];
      int c = ks * 4 + quad;
#pragma unroll
      for (int mt = 0; mt < 4; ++mt) {
        int r = wm + mt * 16 + l16;
        af[mt] = *(const f16x8*)&As[r * 128 + ((c ^ (r & 15)) * 8)];
        int rb = wn + mt * 16 + l16;
        bf[mt] = *(const f16x8*)&Bs[rb * 128 + ((c ^ (rb & 15)) * 8)];
      }
#pragma unroll
      for (int mt = 0; mt < 4; ++mt)
#pragma unroll
        for (int nt = 0; nt < 4; ++nt)
          acc[mt][nt] = __builtin_amdgcn_mfma_f32_16x16x32_f16(af[mt], bf[nt], acc[mt][nt], 0, 0, 0);
    }
  }

#pragma unroll
  for (int mt = 0; mt < 4; ++mt) {
    int row0 = brow + wm + mt * 16 + quad * 4;
#pragma unroll
    for (int nt = 0; nt < 4; ++nt) {
      int col = bcol + wn + nt * 16 + l16;
      f32x4 v = acc[mt][nt];
      if (is_kv) {
        int h = col >> 7, w64 = col & 63;
        if ((col & 127) < 64) {  // K half
#pragma unroll
          for (int r = 0; r < 4; ++r)
            Kp[(size_t)(row0 + r) * INNER_ + h * 64 + w64] = (_Float16)v[r];
        } else {  // V half, transposed store: regs = 4 consecutive keys
          int b = row0 >> 12, key = row0 & 4095;
          f16x4 pk = {(_Float16)v[0], (_Float16)v[1], (_Float16)v[2], (_Float16)v[3]};
          *(f16x4*)&Vt[((size_t)((b * NH_ + h) * DH_) + w64) * LKV_ + key] = pk;
        }
      } else {
#pragma unroll
        for (int r = 0; r < 4; ++r)
          qp16[(size_t)(row0 + r) * 1024 + col] = (_Float16)v[r];
      }
    }
  }
}

// ---------------------------------------------------------------------------
// Flash attention, key-split x2. Grid 1024: bh=id&63 (XCD-sticky),
// qt=(id>>6)&7, half=id>>9. Fixed-shift softmax p=exp(s-8) (scores bounded)
// -> partials are pure sums; each half writes fp32 partial O^T and l.
// NO device fences here (R10 lesson: per-block L2-invalidating fences
// poison all resident blocks' staging latency).
// ---------------------------------------------------------------------------
__global__ __launch_bounds__(256, 2) void attn_f16(
    const _Float16* __restrict__ qp, const _Float16* __restrict__ Kp,
    const _Float16* __restrict__ Vt, const int* __restrict__ cnt,
    float* __restrict__ opart, float* __restrict__ lpart) {
  const int idx = blockIdx.x;
  const int bh = idx & 63, qt = (idx >> 6) & 7, half = idx >> 9;
  const int b = bh >> 4, h = bh & 15;
  __shared__ _Float16 Ks[128 * 64];    // [key][dim], 8-chunk XOR swizzle
  __shared__ _Float16 Vts[64 * 128];   // [dim][key], 16-chunk XOR swizzle
  __shared__ _Float16 Pl[64][136];     // [query][key], +8 pad

  const int tid = threadIdx.x;
  const int wave = tid >> 6, lane = tid & 63;
  const int quad = lane >> 4, l16 = lane & 15;
  const int ro8 = lane >> 3, gch8 = (lane & 7) ^ (ro8 & 7);
  const int ro16 = lane >> 4, ch16 = lane & 15;

  const int qrow = b * LQ_ + qt * 64 + wave * 16 + l16;
  const _Float16* qpr = qp + (size_t)qrow * INNER_ + h * DH_;
  f16x8 qf[2];
  qf[0] = *(const f16x8*)(qpr + quad * 8);
  qf[1] = *(const f16x8*)(qpr + 32 + quad * 8);

  const int c_act = cnt[b];
  const int tiles = (c_act + 127) >> 7;
  const int htiles = (tiles + 1) >> 1;
  const int t0 = half * htiles;
  const int t1 = (half == 0) ? htiles : tiles;

  float l_run = 0.f;
  f32x4 oacc[4];
#pragma unroll
  for (int i = 0; i < 4; ++i) oacc[i] = (f32x4){0.f, 0.f, 0.f, 0.f};

  const _Float16* kb = Kp + (size_t)(b * LKV_) * INNER_ + h * DH_;
  const _Float16* vb = Vt + (size_t)((b * NH_ + h) * DH_) * LKV_;

  for (int t = t0; t < t1; ++t) {
    __syncthreads();  // prev-iter LDS reads done
#pragma unroll
    for (int i = 0; i < 4; ++i) {
      int rbase = wave * 32 + i * 8;
      GLDS(kb + (size_t)(t * 128 + rbase + ro8) * INNER_ + gch8 * 8, &Ks[rbase * 64]);
    }
#pragma unroll
    for (int i = 0; i < 4; ++i) {
      int rbase = wave * 16 + i * 4;
      int row = rbase + ro16;
      int gch = ch16 ^ (row & 15);
      GLDS(vb + (size_t)row * LKV_ + t * 128 + gch * 8, &Vts[rbase * 128]);
    }
    __syncthreads();  // staged data visible

    // S^T = K . Q^T
    f32x4 sacc[8];
#pragma unroll
    for (int i = 0; i < 8; ++i) sacc[i] = (f32x4){0.f, 0.f, 0.f, 0.f};
#pragma unroll
    for (int ks = 0; ks < 2; ++ks) {
      int c = ks * 4 + quad;
#pragma unroll
      for (int mt = 0; mt < 8; ++mt) {
        int krow = mt * 16 + l16;
        f16x8 af = *(const f16x8*)&Ks[krow * 64 + ((c ^ (krow & 7)) * 8)];
        sacc[mt] = __builtin_amdgcn_mfma_f32_16x16x32_f16(af, qf[ks], sacc[mt], 0, 0, 0);
      }
    }
    // scale + tail mask + exp(s-8) + P pack
    const int lim = c_act - t * 128;
    float psloc = 0.f;
#pragma unroll
    for (int mt = 0; mt < 8; ++mt) {
      f16x4 pk;
#pragma unroll
      for (int r = 0; r < 4; ++r) {
        int key = mt * 16 + quad * 4 + r;
        float s = sacc[mt][r] * 0.125f;
        if (key >= lim) s = -1e30f;
        float p = __expf(s - 8.0f);
        psloc += p;
        pk[r] = (_Float16)p;
      }
      *(f16x4*)&Pl[wave * 16 + l16][mt * 16 + quad * 4] = pk;
    }
    psloc += __shfl_xor(psloc, 16);
    psloc += __shfl_xor(psloc, 32);
    l_run += psloc;
    // O^T += V^T . P^T (within-wave Pl dep: lgkmcnt-ordered, no barrier)
#pragma unroll
    for (int ks = 0; ks < 4; ++ks) {
      int c = ks * 4 + quad;
      f16x8 bf = *(const f16x8*)&Pl[wave * 16 + l16][ks * 32 + quad * 8];
#pragma unroll
      for (int mt = 0; mt < 4; ++mt) {
        int drow = mt * 16 + l16;
        f16x8 af = *(const f16x8*)&Vts[drow * 128 + ((c ^ (drow & 15)) * 8)];
        oacc[mt] = __builtin_amdgcn_mfma_f32_16x16x32_f16(af, bf, oacc[mt], 0, 0, 0);
      }
    }
  }

  // write fp32 partials (no normalization)
  float* ob = opart + ((size_t)(half * 2048 + qrow)) * INNER_ + h * DH_;
#pragma unroll
  for (int mt = 0; mt < 4; ++mt)
    *(f32x4*)(ob + mt * 16 + quad * 4) = oacc[mt];
  if (quad == 0) lpart[(size_t)(half * 2048 + qrow) * NH_ + h] = l_run;
}

// ---------------------------------------------------------------------------
// Combine halves + normalize -> ctx16. Grid 2048 (one query row each).
// ---------------------------------------------------------------------------
__global__ __launch_bounds__(256) void attn_fin(const float* __restrict__ opart,
                                                const float* __restrict__ lpart,
                                                _Float16* __restrict__ ctx) {
  int row = blockIdx.x, t = threadIdx.x;
  int h = t >> 4;
  float l = lpart[(size_t)row * NH_ + h] + lpart[(size_t)(2048 + row) * NH_ + h];
  float inv = (l > 0.f) ? 1.f / l : 0.f;
  f32x4 a = *(const f32x4*)(opart + (size_t)row * INNER_ + t * 4);
  f32x4 c = *(const f32x4*)(opart + (size_t)(2048 + row) * INNER_ + t * 4);
  f16x4 o;
#pragma unroll
  for (int r = 0; r < 4; ++r) o[r] = (_Float16)((a[r] + c[r]) * inv);
  *(f16x4*)(ctx + (size_t)row * INNER_ + t * 4) = o;
}

// ---------------------------------------------------------------------------
// Output GEMM: out[2048][1024] f32 = ctx16 @ Wot^T. 64x128 tiles -> 256
// blocks (one per CU), BK=128 -> 8 K-steps.
// ---------------------------------------------------------------------------
__global__ __launch_bounds__(256, 2) void gemm_out(
    const _Float16* __restrict__ A, const _Float16* __restrict__ Bt,
    float* __restrict__ C) {
  const int brow = blockIdx.y * 64, bcol = blockIdx.x * 128;
  __shared__ _Float16 As[64 * 128];
  __shared__ _Float16 Bs[128 * 128];
  const int tid = threadIdx.x;
  const int wave = tid >> 6, lane = tid & 63;
  const int quad = lane >> 4, l16 = lane & 15;
  const int wm = (wave & 1) * 32, wn = (wave >> 1) * 64;
  const int r4 = lane >> 4, ch = lane & 15;

  f32x4 acc[2][4];
#pragma unroll
  for (int i = 0; i < 2; ++i)
#pragma unroll
    for (int j = 0; j < 4; ++j) acc[i][j] = (f32x4){0.f, 0.f, 0.f, 0.f};

  const _Float16* Ab = A + (size_t)brow * 1024;
  const _Float16* Bb = Bt + (size_t)bcol * 1024;

  for (int k0 = 0; k0 < 1024; k0 += 128) {
    __syncthreads();
#pragma unroll
    for (int i = 0; i < 4; ++i) {
      int rbase = wave * 16 + i * 4;
      int row = rbase + r4;
      int g = ch ^ (row & 15);
      GLDS(Ab + (size_t)row * 1024 + k0 + g * 8, &As[rbase * 128]);
    }
#pragma unroll
    for (int i = 0; i < 8; ++i) {
      int rbase = wave * 32 + i * 4;
      int row = rbase + r4;
      int g = ch ^ (row & 15);
      GLDS(Bb + (size_t)row * 1024 + k0 + g * 8, &Bs[rbase * 128]);
    }
    __syncthreads();
#pragma unroll
    for (int ks = 0; ks < 4; ++ks) {
      f16x8 af[2], bf[4];
      int c = ks * 4 + quad;
#pragma unroll
      for (int mt = 0; mt < 2; ++mt) {
        int r = wm + mt * 16 + l16;
        af[mt] = *(const f16x8*)&As[r * 128 + ((c ^ (r & 15)) * 8)];
      }
#pragma unroll
      for (int nt = 0; nt < 4; ++nt) {
        int rb = wn + nt * 16 + l16;
        bf[nt] = *(const f16x8*)&Bs[rb * 128 + ((c ^ (rb & 15)) * 8)];
      }
#pragma unroll
      for (int mt = 0; mt < 2; ++mt)
#pragma unroll
        for (int nt = 0; nt < 4; ++nt)
          acc[mt][nt] = __builtin_amdgcn_mfma_f32_16x16x32_f16(af[mt], bf[nt], acc[mt][nt], 0, 0, 0);
    }
  }

#pragma unroll
  for (int mt = 0; mt < 2; ++mt) {
    int row0 = brow + wm + mt * 16 + quad * 4;
#pragma unroll
    for (int nt = 0; nt < 4; ++nt) {
      int col = bcol + wn + nt * 16 + l16;
      f32x4 v = acc[mt][nt];
#pragma unroll
      for (int r = 0; r < 4; ++r) C[(size_t)(row0 + r) * 1024 + col] = v[r];
    }
  }
}

// ---------------------------------------------------------------------------
extern "C" void kernel_launch(void* const* d_in, const int* in_sizes, int n_in,
                              void* d_out, int out_size, void* d_ws, size_t ws_size,
                              hipStream_t stream) {
  const float* q   = (const float*)d_in[0];
  const float* kv  = (const float*)d_in[1];
  const int* mask  = (const int*)d_in[2];
  const float* Wq  = (const float*)d_in[3];
  const float* Wkv = (const float*)d_in[4];
  const float* Wo  = (const float*)d_in[5];
  float* out = (float*)d_out;

  _Float16* p = (_Float16*)d_ws;
  _Float16* q16   = p; p += (size_t)2048 * 1024;
  _Float16* kv16  = p; p += (size_t)16384 * 1024;  // compacted per-batch
  _Float16* Wqt   = p; p += (size_t)1024 * 1024;
  _Float16* Wkvt  = p; p += (size_t)2048 * 1024;
  _Float16* Wot   = p; p += (size_t)1024 * 1024;
  _Float16* qp16  = p; p += (size_t)2048 * 1024;
  _Float16* Kp    = p; p += (size_t)16384 * 1024;
  _Float16* Vt    = p; p += (size_t)16384 * 1024;
  _Float16* ctx16 = p; p += (size_t)2048 * 1024;
  float* opart = (float*)p; p += (size_t)2 * 4096 * 1024;   // 2x2048x1024 f32
  float* lpart = (float*)p; p += (size_t)2 * 2048 * NH_ * 2; // 2x2048x16 f32
  int* pidx = (int*)p;
  int* cnt  = pidx + 16384;

  scan_mask<<<4, 256, 0, stream>>>(mask, pidx, cnt);
  prep_compact<<<22528, 256, 0, stream>>>(kv, q, Wq, Wkv, Wo, mask, pidx,
                                          kv16, q16, Wqt, Wkvt, Wot);
  proj_f16<<<2176, 256, 0, stream>>>(kv16, Wkvt, q16, Wqt, qp16, Kp, Vt, cnt);
  attn_f16<<<1024, 256, 0, stream>>>(qp16, Kp, Vt, cnt, opart, lpart);
  attn_fin<<<2048, 256, 0, stream>>>(opart, lpart, ctx16);
  gemm_out<<<dim3(8, 32), 256, 0, stream>>>(ctx16, Wot, out);
}